// Round 2
// baseline (5652.276 us; speedup 1.0000x reference)
//
#include <hip/hip_runtime.h>
#include <hip/hip_bf16.h>

#define B_      8
#define HH      32
#define WW      32
#define E_      256
#define HEADS_  8
#define KD_     32
#define FFN_    1024
#define NQ_     64
#define L_      1024
#define SCALING_ 0.17677669529663687f
#define EPS_    1e-6f

// ---- depthwise 3x3 conv + residual --------------------------------------
__global__ void posconv_kernel(const float* __restrict__ x, const float* __restrict__ w,
                               const float* __restrict__ bias, float* __restrict__ out) {
    int e = threadIdx.x;
    int l = blockIdx.x & (L_ - 1);
    int b = blockIdx.x >> 10;
    int hh = l >> 5, ww = l & 31;
    float acc = bias[e];
#pragma unroll
    for (int dh = -1; dh <= 1; ++dh) {
        int h2 = hh + dh; if (h2 < 0 || h2 >= HH) continue;
#pragma unroll
        for (int dw = -1; dw <= 1; ++dw) {
            int w2 = ww + dw; if (w2 < 0 || w2 >= WW) continue;
            acc += x[((b * HH + h2) * WW + w2) * E_ + e] *
                   w[e * 9 + (dh + 1) * 3 + (dw + 1)];
        }
    }
    out[(long)blockIdx.x * E_ + e] = x[(long)blockIdx.x * E_ + e] + acc;
}

// ---- depthwise 5x5 conv -------------------------------------------------
__global__ void lepe_kernel(const float* __restrict__ v, const float* __restrict__ w,
                            const float* __restrict__ bias, float* __restrict__ out) {
    int e = threadIdx.x;
    int l = blockIdx.x & (L_ - 1);
    int b = blockIdx.x >> 10;
    int hh = l >> 5, ww = l & 31;
    float acc = bias[e];
#pragma unroll
    for (int dh = -2; dh <= 2; ++dh) {
        int h2 = hh + dh; if (h2 < 0 || h2 >= HH) continue;
#pragma unroll
        for (int dw = -2; dw <= 2; ++dw) {
            int w2 = ww + dw; if (w2 < 0 || w2 >= WW) continue;
            acc += v[((long)(b * HH + h2) * WW + w2) * E_ + e] *
                   w[e * 25 + (dh + 2) * 5 + (dw + 2)];
        }
    }
    out[(long)blockIdx.x * E_ + e] = acc;
}

// ---- LayerNorm over E=256, one row per 256-thread block -----------------
__global__ void ln_kernel(const float* __restrict__ x, const float* __restrict__ g,
                          const float* __restrict__ b, float* __restrict__ y) {
    __shared__ float red[E_];
    int tid = threadIdx.x;
    long row = blockIdx.x;
    float v = x[row * E_ + tid];
    red[tid] = v; __syncthreads();
    for (int s = 128; s > 0; s >>= 1) { if (tid < s) red[tid] += red[tid + s]; __syncthreads(); }
    float mean = red[0] * (1.0f / E_); __syncthreads();
    float d = v - mean;
    red[tid] = d * d; __syncthreads();
    for (int s = 128; s > 0; s >>= 1) { if (tid < s) red[tid] += red[tid + s]; __syncthreads(); }
    float var = red[0] * (1.0f / E_);
    y[row * E_ + tid] = d * rsqrtf(var + EPS_) * g[tid] + b[tid];
}

// ---- naive row GEMM: C[m,n] = (dot(A[m,:],W[n,:]) + bias[n])*scale ------
__global__ void gemm_kernel(const float* __restrict__ A, const float* __restrict__ W,
                            const float* __restrict__ bias, float* __restrict__ C,
                            const float* __restrict__ resid, int N, int K,
                            float scale, int act) {
    __shared__ float As[1024];
    long m = blockIdx.x;
    int tid = threadIdx.x;
    for (int k = tid; k < K; k += 256) As[k] = A[m * K + k];
    __syncthreads();
    int n = blockIdx.y * 256 + tid;
    const float* wr = W + (long)n * K;
    float acc = 0.f;
    for (int k = 0; k < K; ++k) acc += As[k] * wr[k];
    float v = (acc + bias[n]) * scale;
    if (act) v = 0.5f * v * (1.0f + erff(v * 0.70710678118654752f));
    if (resid) v += resid[m * N + n];
    C[m * N + n] = v;
}

// ---- attention: one block per (b, head, query row) ----------------------
__global__ void attn_kernel(const float* __restrict__ Q, const float* __restrict__ K,
                            const float* __restrict__ V, const float* __restrict__ mask,
                            const float* __restrict__ lepe, float* __restrict__ out,
                            int nq, int lk) {
    __shared__ float qrow[KD_];
    __shared__ float red[256];
    __shared__ float probs[L_];
    int tid = threadIdx.x;
    int qi = blockIdx.x % nq;
    int h  = (blockIdx.x / nq) % HEADS_;
    int b  = blockIdx.x / (nq * HEADS_);
    if (tid < KD_) qrow[tid] = Q[((long)(b * nq + qi)) * E_ + h * KD_ + tid];
    __syncthreads();
    const float* Kb = K + (long)b * lk * E_ + h * KD_;
    int nj = lk / 256;
    float s[4]; float lmax = -1e30f;
    for (int jj = 0; jj < nj; ++jj) {
        int j = jj * 256 + tid;
        const float* kr = Kb + (long)j * E_;
        float acc = 0.f;
#pragma unroll
        for (int d = 0; d < KD_; ++d) acc += qrow[d] * kr[d];
        if (mask) acc += mask[((long)h * lk + qi) * lk + j];
        s[jj] = acc; lmax = fmaxf(lmax, acc);
    }
    red[tid] = lmax; __syncthreads();
    for (int st = 128; st > 0; st >>= 1) { if (tid < st) red[tid] = fmaxf(red[tid], red[tid + st]); __syncthreads(); }
    float mx = red[0]; __syncthreads();
    float lsum = 0.f;
    for (int jj = 0; jj < nj; ++jj) {
        float p = expf(s[jj] - mx);
        probs[jj * 256 + tid] = p; lsum += p;
    }
    red[tid] = lsum; __syncthreads();
    for (int st = 128; st > 0; st >>= 1) { if (tid < st) red[tid] += red[tid + st]; __syncthreads(); }
    float denom = red[0]; __syncthreads();
    int d = tid & 31, g = tid >> 5;
    int chunk = lk / 8;
    const float* Vb = V + (long)b * lk * E_ + h * KD_;
    float acc = 0.f;
    for (int j = g * chunk; j < g * chunk + chunk; ++j) acc += probs[j] * Vb[(long)j * E_ + d];
    red[tid] = acc; __syncthreads();
    if (tid < KD_) {
        float tot = 0.f;
#pragma unroll
        for (int gg = 0; gg < 8; ++gg) tot += red[gg * 32 + tid];
        float o = tot / denom;
        long oi = ((long)(b * nq + qi)) * E_ + h * KD_ + tid;
        if (lepe) o += lepe[oi];
        out[oi] = o;
    }
}

// ---- in-place rotary theta shift on pairs -------------------------------
__global__ void theta_kernel(float* __restrict__ buf, const float* __restrict__ sinp,
                             const float* __restrict__ cosp) {
    int p = blockIdx.x * 256 + threadIdx.x;
    long base = (long)p * 2;
    int e0 = (int)(base & 255);
    int l  = (int)((base >> 8) & 1023);
    int d0 = e0 & 31;
    float c0 = cosp[l * 32 + d0], c1 = cosp[l * 32 + d0 + 1];
    float s0 = sinp[l * 32 + d0], s1 = sinp[l * 32 + d0 + 1];
    float x0 = buf[base], x1 = buf[base + 1];
    buf[base]     = x0 * c0 - x1 * s0;
    buf[base + 1] = x1 * c1 + x0 * s1;
}

extern "C" void kernel_launch(void* const* d_in, const int* in_sizes, int n_in,
                              void* d_out, int out_size, void* d_ws, size_t ws_size,
                              hipStream_t stream) {
    const float* x        = (const float*)d_in[0];
    const float* queries  = (const float*)d_in[1];
    const float* sinp     = (const float*)d_in[2];
    const float* cosp     = (const float*)d_in[3];
    const float* mask     = (const float*)d_in[4];
    const float* ln1_g    = (const float*)d_in[5];
    const float* ln1_b    = (const float*)d_in[6];
    const float* ln2_g    = (const float*)d_in[7];
    const float* ln2_b    = (const float*)d_in[8];
    const float* wq       = (const float*)d_in[9];
    const float* bq       = (const float*)d_in[10];
    const float* wk       = (const float*)d_in[11];
    const float* bk       = (const float*)d_in[12];
    const float* wv       = (const float*)d_in[13];
    const float* bv       = (const float*)d_in[14];
    const float* lepe_w   = (const float*)d_in[15];
    const float* lepe_b   = (const float*)d_in[16];
    const float* wo       = (const float*)d_in[17];
    const float* bo       = (const float*)d_in[18];
    const float* fc1_w    = (const float*)d_in[19];
    const float* fc1_b    = (const float*)d_in[20];
    const float* fc2_w    = (const float*)d_in[21];
    const float* fc2_b    = (const float*)d_in[22];
    const float* pos_w    = (const float*)d_in[23];
    const float* pos_b    = (const float*)d_in[24];
    const float* ca_in_w  = (const float*)d_in[25];
    const float* ca_in_b  = (const float*)d_in[26];
    const float* ca_out_w = (const float*)d_in[27];
    const float* ca_out_b = (const float*)d_in[28];

    float* ws = (float*)d_ws;
    const long SZ = (long)B_ * L_ * E_;       // 2,097,152 floats
    float* X    = ws;                // tile 0
    float* HN   = ws + SZ;           // tile 1
    float* Qb   = ws + 2 * SZ;       // tile 2
    float* Kb   = ws + 3 * SZ;       // tile 3
    float* Vb   = ws + 4 * SZ;       // tile 4
    float* LEP  = ws + 5 * SZ;       // tile 5
    float* ATT  = HN;                // HN dead after q/k/v gemms
    float* HID  = Qb;                // 4*SZ contiguous: tiles 2..5
    // cross-attention small buffers (each 131072 floats) inside HN tile:
    float* QLN  = HN;
    float* QP   = HN + 131072;
    float* CAO  = HN + 262144;
    float* Q2   = HN + 393216;
    float* KP   = Qb;
    float* VP   = Kb;
    float* QHID = Vb;                // 512*1024

    float* XOUT = (float*)d_out;            // final x (2097152)
    float* QOUT = (float*)d_out + 2097152;  // final queries (131072)

    dim3 blk(256);
    const int rows = B_ * L_;  // 8192

    // ---- main path ----
    posconv_kernel<<<rows, blk, 0, stream>>>(x, pos_w, pos_b, X);
    ln_kernel<<<rows, blk, 0, stream>>>(X, ln1_g, ln1_b, HN);
    gemm_kernel<<<dim3(rows, 1), blk, 0, stream>>>(HN, wq, bq, Qb, nullptr, 256, 256, 1.0f, 0);
    gemm_kernel<<<dim3(rows, 1), blk, 0, stream>>>(HN, wk, bk, Kb, nullptr, 256, 256, SCALING_, 0);
    gemm_kernel<<<dim3(rows, 1), blk, 0, stream>>>(HN, wv, bv, Vb, nullptr, 256, 256, 1.0f, 0);
    lepe_kernel<<<rows, blk, 0, stream>>>(Vb, lepe_w, lepe_b, LEP);
    theta_kernel<<<4096, blk, 0, stream>>>(Qb, sinp, cosp);
    theta_kernel<<<4096, blk, 0, stream>>>(Kb, sinp, cosp);
    attn_kernel<<<B_ * HEADS_ * L_, blk, 0, stream>>>(Qb, Kb, Vb, mask, LEP, ATT, L_, L_);
    gemm_kernel<<<dim3(rows, 1), blk, 0, stream>>>(ATT, wo, bo, X, X, 256, 256, 1.0f, 0);
    ln_kernel<<<rows, blk, 0, stream>>>(X, ln2_g, ln2_b, HN);
    gemm_kernel<<<dim3(rows, 4), blk, 0, stream>>>(HN, fc1_w, fc1_b, HID, nullptr, 1024, 256, 1.0f, 1);
    gemm_kernel<<<dim3(rows, 1), blk, 0, stream>>>(HID, fc2_w, fc2_b, XOUT, X, 256, 1024, 1.0f, 0);

    // ---- cross-attention path (K/V source = final x in d_out) ----
    ln_kernel<<<B_ * NQ_, blk, 0, stream>>>(queries, ln1_g, ln1_b, QLN);
    gemm_kernel<<<dim3(B_ * NQ_, 1), blk, 0, stream>>>(QLN, ca_in_w, ca_in_b, QP, nullptr, 256, 256, 1.0f, 0);
    gemm_kernel<<<dim3(rows, 1), blk, 0, stream>>>(XOUT, ca_in_w + 65536, ca_in_b + 256, KP, nullptr, 256, 256, SCALING_, 0);
    gemm_kernel<<<dim3(rows, 1), blk, 0, stream>>>(XOUT, ca_in_w + 131072, ca_in_b + 512, VP, nullptr, 256, 256, 1.0f, 0);
    attn_kernel<<<B_ * HEADS_ * NQ_, blk, 0, stream>>>(QP, KP, VP, nullptr, nullptr, CAO, NQ_, L_);
    gemm_kernel<<<dim3(B_ * NQ_, 1), blk, 0, stream>>>(CAO, ca_out_w, ca_out_b, Q2, queries, 256, 256, 1.0f, 0);
    ln_kernel<<<B_ * NQ_, blk, 0, stream>>>(Q2, ln2_g, ln2_b, QLN);
    gemm_kernel<<<dim3(B_ * NQ_, 4), blk, 0, stream>>>(QLN, fc1_w, fc1_b, QHID, nullptr, 1024, 256, 1.0f, 1);
    gemm_kernel<<<dim3(B_ * NQ_, 1), blk, 0, stream>>>(QHID, fc2_w, fc2_b, QOUT, Q2, 256, 1024, 1.0f, 0);
}

// Round 3
// 826.085 us; speedup vs baseline: 6.8422x; 6.8422x over previous
//
#include <hip/hip_runtime.h>
#include <hip/hip_bf16.h>

#define B_      8
#define HH      32
#define WW      32
#define E_      256
#define HEADS_  8
#define KD_     32
#define FFN_    1024
#define NQ_     64
#define L_      1024
#define SCALING_ 0.17677669529663687f
#define EPS_    1e-6f

typedef short bf16x8 __attribute__((ext_vector_type(8)));
typedef float f32x4 __attribute__((ext_vector_type(4)));

__device__ __forceinline__ unsigned short f2bf(float f) {
    __hip_bfloat16 h = __float2bfloat16(f);
    return *reinterpret_cast<unsigned short*>(&h);
}

// ---- depthwise 3x3 conv + residual --------------------------------------
__global__ void posconv_kernel(const float* __restrict__ x, const float* __restrict__ w,
                               const float* __restrict__ bias, float* __restrict__ out) {
    int e = threadIdx.x;
    int l = blockIdx.x & (L_ - 1);
    int b = blockIdx.x >> 10;
    int hh = l >> 5, ww = l & 31;
    float acc = bias[e];
#pragma unroll
    for (int dh = -1; dh <= 1; ++dh) {
        int h2 = hh + dh; if (h2 < 0 || h2 >= HH) continue;
#pragma unroll
        for (int dw = -1; dw <= 1; ++dw) {
            int w2 = ww + dw; if (w2 < 0 || w2 >= WW) continue;
            acc += x[((b * HH + h2) * WW + w2) * E_ + e] *
                   w[e * 9 + (dh + 1) * 3 + (dw + 1)];
        }
    }
    out[(long)blockIdx.x * E_ + e] = x[(long)blockIdx.x * E_ + e] + acc;
}

// ---- depthwise 5x5 conv -------------------------------------------------
__global__ void lepe_kernel(const float* __restrict__ v, const float* __restrict__ w,
                            const float* __restrict__ bias, float* __restrict__ out) {
    int e = threadIdx.x;
    int l = blockIdx.x & (L_ - 1);
    int b = blockIdx.x >> 10;
    int hh = l >> 5, ww = l & 31;
    float acc = bias[e];
#pragma unroll
    for (int dh = -2; dh <= 2; ++dh) {
        int h2 = hh + dh; if (h2 < 0 || h2 >= HH) continue;
#pragma unroll
        for (int dw = -2; dw <= 2; ++dw) {
            int w2 = ww + dw; if (w2 < 0 || w2 >= WW) continue;
            acc += v[((long)(b * HH + h2) * WW + w2) * E_ + e] *
                   w[e * 25 + (dh + 2) * 5 + (dw + 2)];
        }
    }
    out[(long)blockIdx.x * E_ + e] = acc;
}

// ---- LayerNorm over E=256 -----------------------------------------------
__global__ void ln_kernel(const float* __restrict__ x, const float* __restrict__ g,
                          const float* __restrict__ b, float* __restrict__ y) {
    __shared__ float red[E_];
    int tid = threadIdx.x;
    long row = blockIdx.x;
    float v = x[row * E_ + tid];
    red[tid] = v; __syncthreads();
    for (int s = 128; s > 0; s >>= 1) { if (tid < s) red[tid] += red[tid + s]; __syncthreads(); }
    float mean = red[0] * (1.0f / E_); __syncthreads();
    float d = v - mean;
    red[tid] = d * d; __syncthreads();
    for (int s = 128; s > 0; s >>= 1) { if (tid < s) red[tid] += red[tid + s]; __syncthreads(); }
    float var = red[0] * (1.0f / E_);
    y[row * E_ + tid] = d * rsqrtf(var + EPS_) * g[tid] + b[tid];
}

// ---- MFMA bf16 GEMM: C[m,n] = (dot(A[m,:],W[n,:]) + bias[n])*scale ------
// BM=128, BN=64, BK=32. 4 waves: 2x2, each wave 64x32 via 4x2 mfma 16x16x32.
__global__ __launch_bounds__(256) void gemm_mfma(
        const float* __restrict__ A, const float* __restrict__ W,
        const float* __restrict__ bias, float* __restrict__ C,
        const float* __restrict__ resid, int M, int N, int K,
        float scale, int act) {
    __shared__ __align__(16) unsigned short As[128 * 40];
    __shared__ __align__(16) unsigned short Ws[64 * 40];
    int tid = threadIdx.x;
    int wave = tid >> 6, lane = tid & 63;
    int quad = lane >> 4, l16 = lane & 15;
    int wm = wave >> 1, wn = wave & 1;
    long mBase = (long)blockIdx.x * 128;
    long nBase = (long)blockIdx.y * 64;

    f32x4 acc[4][2];
#pragma unroll
    for (int i = 0; i < 4; ++i)
#pragma unroll
        for (int j = 0; j < 2; ++j) acc[i][j] = (f32x4){0.f, 0.f, 0.f, 0.f};

    for (int kt = 0; kt < K; kt += 32) {
#pragma unroll
        for (int r = 0; r < 4; ++r) {
            int idx = tid + 256 * r;
            int row = idx >> 3, kq = idx & 7;
            float4 v = *reinterpret_cast<const float4*>(A + (mBase + row) * (long)K + kt + kq * 4);
            int o = row * 40 + kq * 4;
            As[o] = f2bf(v.x); As[o + 1] = f2bf(v.y); As[o + 2] = f2bf(v.z); As[o + 3] = f2bf(v.w);
        }
#pragma unroll
        for (int r = 0; r < 2; ++r) {
            int idx = tid + 256 * r;
            int row = idx >> 3, kq = idx & 7;
            float4 v = *reinterpret_cast<const float4*>(W + (nBase + row) * (long)K + kt + kq * 4);
            int o = row * 40 + kq * 4;
            Ws[o] = f2bf(v.x); Ws[o + 1] = f2bf(v.y); Ws[o + 2] = f2bf(v.z); Ws[o + 3] = f2bf(v.w);
        }
        __syncthreads();
        bf16x8 af[4], bfr[2];
#pragma unroll
        for (int i = 0; i < 4; ++i)
            af[i] = *reinterpret_cast<const bf16x8*>(&As[(wm * 64 + i * 16 + l16) * 40 + quad * 8]);
#pragma unroll
        for (int j = 0; j < 2; ++j)
            bfr[j] = *reinterpret_cast<const bf16x8*>(&Ws[(wn * 32 + j * 16 + l16) * 40 + quad * 8]);
#pragma unroll
        for (int i = 0; i < 4; ++i)
#pragma unroll
            for (int j = 0; j < 2; ++j)
                acc[i][j] = __builtin_amdgcn_mfma_f32_16x16x32_bf16(af[i], bfr[j], acc[i][j], 0, 0, 0);
        __syncthreads();
    }

#pragma unroll
    for (int i = 0; i < 4; ++i)
#pragma unroll
        for (int j = 0; j < 2; ++j) {
            long n = nBase + wn * 32 + j * 16 + l16;
            float bn = bias[n];
#pragma unroll
            for (int r = 0; r < 4; ++r) {
                long m = mBase + wm * 64 + i * 16 + quad * 4 + r;
                float v = (acc[i][j][r] + bn) * scale;
                if (act) v = 0.5f * v * (1.0f + erff(v * 0.70710678118654752f));
                if (resid) v += resid[m * N + n];
                C[m * N + n] = v;
            }
        }
}

// ---- attention v2: block per (b, h, 64-query tile) -----------------------
// lane = query; keys iterated wave-uniformly (K/V rows scalar-loaded);
// mask tile staged into LDS (stride 129 -> conflict-free column reads).
__global__ __launch_bounds__(256) void attn2_kernel(
        const float* __restrict__ Q, const float* __restrict__ K,
        const float* __restrict__ V, const float* __restrict__ mask,
        const float* __restrict__ lepe, float* __restrict__ out,
        int nq, int lk) {
    __shared__ float smem[8704];
    int tid = threadIdx.x;
    int wave = tid >> 6, lane = tid & 63;
    int qt = blockIdx.x, h = blockIdx.y, b = blockIdx.z;

    float qreg[32];
    long qrow = ((long)b * nq + qt * 64 + lane) * E_ + h * KD_;
#pragma unroll
    for (int d = 0; d < 32; ++d) qreg[d] = Q[qrow + d];

    float o[32];
#pragma unroll
    for (int d = 0; d < 32; ++d) o[d] = 0.f;
    float lsum = 0.f;

    for (int kb = 0; kb < lk; kb += 128) {
        if (mask) {
            __syncthreads();
#pragma unroll
            for (int r = 0; r < 8; ++r) {
                int idx4 = tid + 256 * r;
                int row = idx4 >> 5, jq = idx4 & 31;
                float4 v = *reinterpret_cast<const float4*>(
                    &mask[((long)h * lk + qt * 64 + row) * lk + kb + jq * 4]);
                int off = row * 129 + jq * 4;
                smem[off] = v.x; smem[off + 1] = v.y; smem[off + 2] = v.z; smem[off + 3] = v.w;
            }
            __syncthreads();
        }
        for (int jj = 0; jj < 32; ++jj) {
            int jrow = __builtin_amdgcn_readfirstlane(b * lk + kb + wave * 32 + jj);
            const float* Kr = K + (long)jrow * E_ + h * KD_;
            float s = mask ? smem[lane * 129 + wave * 32 + jj] : 0.f;
#pragma unroll
            for (int d = 0; d < 32; ++d) s += qreg[d] * Kr[d];
            float p = __expf(s);
            lsum += p;
            const float* Vr = V + (long)jrow * E_ + h * KD_;
#pragma unroll
            for (int d = 0; d < 32; ++d) o[d] += p * Vr[d];
        }
    }

    // combine 4 waves (disjoint key subsets)
    __syncthreads();
    float* OW = smem;            // [4*64][33]
    float* LW = smem + 8448;     // [256]
#pragma unroll
    for (int d = 0; d < 32; ++d) OW[(wave * 64 + lane) * 33 + d] = o[d];
    LW[wave * 64 + lane] = lsum;
    __syncthreads();
    int q2 = tid >> 2, dg = tid & 3;
    float l = LW[q2] + LW[64 + q2] + LW[128 + q2] + LW[192 + q2];
#pragma unroll
    for (int i = 0; i < 8; ++i) {
        int d = dg * 8 + i;
        float v = OW[q2 * 33 + d] + OW[(64 + q2) * 33 + d] +
                  OW[(128 + q2) * 33 + d] + OW[(192 + q2) * 33 + d];
        v /= l;
        long oi = ((long)b * nq + qt * 64 + q2) * E_ + h * KD_ + d;
        if (lepe) v += lepe[oi];
        out[oi] = v;
    }
}

// ---- in-place rotary theta shift ----------------------------------------
__global__ void theta_kernel(float* __restrict__ buf, const float* __restrict__ sinp,
                             const float* __restrict__ cosp) {
    int p = blockIdx.x * 256 + threadIdx.x;
    long base = (long)p * 2;
    int e0 = (int)(base & 255);
    int l  = (int)((base >> 8) & 1023);
    int d0 = e0 & 31;
    float c0 = cosp[l * 32 + d0], c1 = cosp[l * 32 + d0 + 1];
    float s0 = sinp[l * 32 + d0], s1 = sinp[l * 32 + d0 + 1];
    float x0 = buf[base], x1 = buf[base + 1];
    buf[base]     = x0 * c0 - x1 * s0;
    buf[base + 1] = x1 * c1 + x0 * s1;
}

extern "C" void kernel_launch(void* const* d_in, const int* in_sizes, int n_in,
                              void* d_out, int out_size, void* d_ws, size_t ws_size,
                              hipStream_t stream) {
    const float* x        = (const float*)d_in[0];
    const float* queries  = (const float*)d_in[1];
    const float* sinp     = (const float*)d_in[2];
    const float* cosp     = (const float*)d_in[3];
    const float* mask     = (const float*)d_in[4];
    const float* ln1_g    = (const float*)d_in[5];
    const float* ln1_b    = (const float*)d_in[6];
    const float* ln2_g    = (const float*)d_in[7];
    const float* ln2_b    = (const float*)d_in[8];
    const float* wq       = (const float*)d_in[9];
    const float* bq       = (const float*)d_in[10];
    const float* wk       = (const float*)d_in[11];
    const float* bk       = (const float*)d_in[12];
    const float* wv       = (const float*)d_in[13];
    const float* bv       = (const float*)d_in[14];
    const float* lepe_w   = (const float*)d_in[15];
    const float* lepe_b   = (const float*)d_in[16];
    const float* wo       = (const float*)d_in[17];
    const float* bo       = (const float*)d_in[18];
    const float* fc1_w    = (const float*)d_in[19];
    const float* fc1_b    = (const float*)d_in[20];
    const float* fc2_w    = (const float*)d_in[21];
    const float* fc2_b    = (const float*)d_in[22];
    const float* pos_w    = (const float*)d_in[23];
    const float* pos_b    = (const float*)d_in[24];
    const float* ca_in_w  = (const float*)d_in[25];
    const float* ca_in_b  = (const float*)d_in[26];
    const float* ca_out_w = (const float*)d_in[27];
    const float* ca_out_b = (const float*)d_in[28];

    float* ws = (float*)d_ws;
    const long SZ = (long)B_ * L_ * E_;       // 2,097,152 floats
    float* X    = ws;
    float* HN   = ws + SZ;
    float* Qb   = ws + 2 * SZ;
    float* Kb   = ws + 3 * SZ;
    float* Vb   = ws + 4 * SZ;
    float* LEP  = ws + 5 * SZ;
    float* ATT  = HN;
    float* HID  = Qb;                // spans tiles 2..5
    float* QLN  = HN;
    float* QP   = HN + 131072;
    float* CAO  = HN + 262144;
    float* Q2   = HN + 393216;
    float* KP   = Qb;
    float* VP   = Kb;
    float* QHID = Vb;

    float* XOUT = (float*)d_out;
    float* QOUT = (float*)d_out + 2097152;

    dim3 blk(256);
    const int rows = B_ * L_;  // 8192

    // ---- main path ----
    posconv_kernel<<<rows, blk, 0, stream>>>(x, pos_w, pos_b, X);
    ln_kernel<<<rows, blk, 0, stream>>>(X, ln1_g, ln1_b, HN);
    gemm_mfma<<<dim3(64, 4), blk, 0, stream>>>(HN, wq, bq, Qb, nullptr, rows, 256, 256, 1.0f, 0);
    gemm_mfma<<<dim3(64, 4), blk, 0, stream>>>(HN, wk, bk, Kb, nullptr, rows, 256, 256, SCALING_, 0);
    gemm_mfma<<<dim3(64, 4), blk, 0, stream>>>(HN, wv, bv, Vb, nullptr, rows, 256, 256, 1.0f, 0);
    lepe_kernel<<<rows, blk, 0, stream>>>(Vb, lepe_w, lepe_b, LEP);
    theta_kernel<<<4096, blk, 0, stream>>>(Qb, sinp, cosp);
    theta_kernel<<<4096, blk, 0, stream>>>(Kb, sinp, cosp);
    attn2_kernel<<<dim3(16, 8, 8), blk, 0, stream>>>(Qb, Kb, Vb, mask, LEP, ATT, L_, L_);
    gemm_mfma<<<dim3(64, 4), blk, 0, stream>>>(ATT, wo, bo, X, X, rows, 256, 256, 1.0f, 0);
    ln_kernel<<<rows, blk, 0, stream>>>(X, ln2_g, ln2_b, HN);
    gemm_mfma<<<dim3(64, 16), blk, 0, stream>>>(HN, fc1_w, fc1_b, HID, nullptr, rows, 1024, 256, 1.0f, 1);
    gemm_mfma<<<dim3(64, 4), blk, 0, stream>>>(HID, fc2_w, fc2_b, XOUT, X, rows, 256, 1024, 1.0f, 0);

    // ---- cross-attention path ----
    ln_kernel<<<B_ * NQ_, blk, 0, stream>>>(queries, ln1_g, ln1_b, QLN);
    gemm_mfma<<<dim3(4, 4), blk, 0, stream>>>(QLN, ca_in_w, ca_in_b, QP, nullptr, 512, 256, 256, 1.0f, 0);
    gemm_mfma<<<dim3(64, 4), blk, 0, stream>>>(XOUT, ca_in_w + 65536, ca_in_b + 256, KP, nullptr, rows, 256, 256, SCALING_, 0);
    gemm_mfma<<<dim3(64, 4), blk, 0, stream>>>(XOUT, ca_in_w + 131072, ca_in_b + 512, VP, nullptr, rows, 256, 256, 1.0f, 0);
    attn2_kernel<<<dim3(1, 8, 8), blk, 0, stream>>>(QP, KP, VP, nullptr, nullptr, CAO, NQ_, L_);
    gemm_mfma<<<dim3(4, 4), blk, 0, stream>>>(CAO, ca_out_w, ca_out_b, Q2, queries, 512, 256, 256, 1.0f, 0);
    ln_kernel<<<B_ * NQ_, blk, 0, stream>>>(Q2, ln2_g, ln2_b, QLN);
    gemm_mfma<<<dim3(4, 16), blk, 0, stream>>>(QLN, fc1_w, fc1_b, QHID, nullptr, 512, 1024, 256, 1.0f, 1);
    gemm_mfma<<<dim3(4, 4), blk, 0, stream>>>(QHID, fc2_w, fc2_b, QOUT, Q2, 512, 256, 1024, 1.0f, 0);
}

// Round 4
// 504.582 us; speedup vs baseline: 11.2019x; 1.6372x over previous
//
#include <hip/hip_runtime.h>
#include <hip/hip_bf16.h>

#define B_      8
#define HH      32
#define WW      32
#define E_      256
#define HEADS_  8
#define KD_     32
#define FFN_    1024
#define NQ_     64
#define L_      1024
#define SCALING_ 0.17677669529663687f
#define EPS_    1e-6f

typedef short bf16x8 __attribute__((ext_vector_type(8)));
typedef float f32x4 __attribute__((ext_vector_type(4)));
typedef unsigned short ushort_t;

__device__ __forceinline__ ushort_t f2bf(float f) {
    __hip_bfloat16 h = __float2bfloat16(f);
    return *reinterpret_cast<ushort_t*>(&h);
}
__device__ __forceinline__ float bf2f(ushort_t u) {
    __hip_bfloat16 h = *reinterpret_cast<__hip_bfloat16*>(&u);
    return __bfloat162float(h);
}

// ---- fused depthwise 3x3 conv + residual + LayerNorm --------------------
__global__ void posconv_ln_kernel(const float* __restrict__ x, const float* __restrict__ w,
                                  const float* __restrict__ bias,
                                  const float* __restrict__ g, const float* __restrict__ bb,
                                  float* __restrict__ X, ushort_t* __restrict__ HN) {
    __shared__ float red[E_];
    int e = threadIdx.x;
    int l = blockIdx.x & (L_ - 1);
    int b = blockIdx.x >> 10;
    int hh = l >> 5, ww = l & 31;
    float acc = bias[e];
#pragma unroll
    for (int dh = -1; dh <= 1; ++dh) {
        int h2 = hh + dh; if (h2 < 0 || h2 >= HH) continue;
#pragma unroll
        for (int dw = -1; dw <= 1; ++dw) {
            int w2 = ww + dw; if (w2 < 0 || w2 >= WW) continue;
            acc += x[((b * HH + h2) * WW + w2) * E_ + e] *
                   w[e * 9 + (dh + 1) * 3 + (dw + 1)];
        }
    }
    float xv = x[(long)blockIdx.x * E_ + e] + acc;
    X[(long)blockIdx.x * E_ + e] = xv;
    // LayerNorm
    red[e] = xv; __syncthreads();
    for (int s = 128; s > 0; s >>= 1) { if (e < s) red[e] += red[e + s]; __syncthreads(); }
    float mean = red[0] * (1.0f / E_); __syncthreads();
    float d = xv - mean;
    red[e] = d * d; __syncthreads();
    for (int s = 128; s > 0; s >>= 1) { if (e < s) red[e] += red[e + s]; __syncthreads(); }
    float var = red[0] * (1.0f / E_);
    HN[(long)blockIdx.x * E_ + e] = f2bf(d * rsqrtf(var + EPS_) * g[e] + bb[e]);
}

// ---- depthwise 5x5 conv (f32 in/out) ------------------------------------
__global__ void lepe_kernel(const float* __restrict__ v, const float* __restrict__ w,
                            const float* __restrict__ bias, float* __restrict__ out) {
    int e = threadIdx.x;
    int l = blockIdx.x & (L_ - 1);
    int b = blockIdx.x >> 10;
    int hh = l >> 5, ww = l & 31;
    float acc = bias[e];
#pragma unroll
    for (int dh = -2; dh <= 2; ++dh) {
        int h2 = hh + dh; if (h2 < 0 || h2 >= HH) continue;
#pragma unroll
        for (int dw = -2; dw <= 2; ++dw) {
            int w2 = ww + dw; if (w2 < 0 || w2 >= WW) continue;
            acc += v[((long)(b * HH + h2) * WW + w2) * E_ + e] *
                   w[e * 25 + (dh + 2) * 5 + (dw + 2)];
        }
    }
    out[(long)blockIdx.x * E_ + e] = acc;
}

// ---- LayerNorm f32 -> bf16 ----------------------------------------------
__global__ void ln_kernel(const float* __restrict__ x, const float* __restrict__ g,
                          const float* __restrict__ b, ushort_t* __restrict__ y) {
    __shared__ float red[E_];
    int tid = threadIdx.x;
    long row = blockIdx.x;
    float v = x[row * E_ + tid];
    red[tid] = v; __syncthreads();
    for (int s = 128; s > 0; s >>= 1) { if (tid < s) red[tid] += red[tid + s]; __syncthreads(); }
    float mean = red[0] * (1.0f / E_); __syncthreads();
    float d = v - mean;
    red[tid] = d * d; __syncthreads();
    for (int s = 128; s > 0; s >>= 1) { if (tid < s) red[tid] += red[tid + s]; __syncthreads(); }
    float var = red[0] * (1.0f / E_);
    y[row * E_ + tid] = f2bf(d * rsqrtf(var + EPS_) * g[tid] + b[tid]);
}

// ---- templated MFMA GEMM ------------------------------------------------
// C[m,n] = f((dot(A[m,:],W[n,:]) + bias[n])*scale) (+resid)  BM=128 BN=64 BK=32
template<int ABF16, int OBF16, int THETA, int ACT>
__global__ __launch_bounds__(256) void gemm_t(
        const void* __restrict__ Ap, const float* __restrict__ W,
        const float* __restrict__ bias, void* __restrict__ Cp,
        const float* __restrict__ resid, int M, int N, int K,
        float scale, const float* __restrict__ sinp, const float* __restrict__ cosp) {
    __shared__ __align__(16) ushort_t As[128 * 40];
    __shared__ __align__(16) ushort_t Ws[64 * 40];
    int tid = threadIdx.x;
    int wave = tid >> 6, lane = tid & 63;
    int quad = lane >> 4, l16 = lane & 15;
    int wm = wave >> 1, wn = wave & 1;
    long mBase = (long)blockIdx.x * 128;
    long nBase = (long)blockIdx.y * 64;

    f32x4 acc[4][2];
#pragma unroll
    for (int i = 0; i < 4; ++i)
#pragma unroll
        for (int j = 0; j < 2; ++j) acc[i][j] = (f32x4){0.f, 0.f, 0.f, 0.f};

    for (int kt = 0; kt < K; kt += 32) {
        if (ABF16) {
            const ushort_t* Ab = (const ushort_t*)Ap;
#pragma unroll
            for (int r = 0; r < 2; ++r) {
                int c = tid + 256 * r;
                int row = c >> 2, q = c & 3;
                uint4 v = *reinterpret_cast<const uint4*>(Ab + (mBase + row) * (long)K + kt + q * 8);
                *reinterpret_cast<uint4*>(&As[row * 40 + q * 8]) = v;
            }
        } else {
            const float* Af = (const float*)Ap;
#pragma unroll
            for (int r = 0; r < 4; ++r) {
                int idx = tid + 256 * r;
                int row = idx >> 3, kq = idx & 7;
                float4 v = *reinterpret_cast<const float4*>(Af + (mBase + row) * (long)K + kt + kq * 4);
                unsigned int p0 = f2bf(v.x) | ((unsigned int)f2bf(v.y) << 16);
                unsigned int p1 = f2bf(v.z) | ((unsigned int)f2bf(v.w) << 16);
                *reinterpret_cast<unsigned int*>(&As[row * 40 + kq * 4]) = p0;
                *reinterpret_cast<unsigned int*>(&As[row * 40 + kq * 4 + 2]) = p1;
            }
        }
#pragma unroll
        for (int r = 0; r < 2; ++r) {
            int idx = tid + 256 * r;
            int row = idx >> 3, kq = idx & 7;
            float4 v = *reinterpret_cast<const float4*>(W + (nBase + row) * (long)K + kt + kq * 4);
            unsigned int p0 = f2bf(v.x) | ((unsigned int)f2bf(v.y) << 16);
            unsigned int p1 = f2bf(v.z) | ((unsigned int)f2bf(v.w) << 16);
            *reinterpret_cast<unsigned int*>(&Ws[row * 40 + kq * 4]) = p0;
            *reinterpret_cast<unsigned int*>(&Ws[row * 40 + kq * 4 + 2]) = p1;
        }
        __syncthreads();
        bf16x8 af[4], bfr[2];
#pragma unroll
        for (int i = 0; i < 4; ++i)
            af[i] = *reinterpret_cast<const bf16x8*>(&As[(wm * 64 + i * 16 + l16) * 40 + quad * 8]);
#pragma unroll
        for (int j = 0; j < 2; ++j)
            bfr[j] = *reinterpret_cast<const bf16x8*>(&Ws[(wn * 32 + j * 16 + l16) * 40 + quad * 8]);
#pragma unroll
        for (int i = 0; i < 4; ++i)
#pragma unroll
            for (int j = 0; j < 2; ++j)
                acc[i][j] = __builtin_amdgcn_mfma_f32_16x16x32_bf16(af[i], bfr[j], acc[i][j], 0, 0, 0);
        __syncthreads();
    }

#pragma unroll
    for (int i = 0; i < 4; ++i)
#pragma unroll
        for (int j = 0; j < 2; ++j) {
            long n = nBase + wn * 32 + j * 16 + l16;
            float bn = bias[n];
#pragma unroll
            for (int r = 0; r < 4; ++r) {
                long m = mBase + wm * 64 + i * 16 + quad * 4 + r;
                float v = (acc[i][j][r] + bn) * scale;
                if (THETA) {
                    float other = __shfl_xor(v, 1);
                    int l = (int)(m & (L_ - 1));
                    int d = (int)(n & 31);
                    float cc = cosp[l * 32 + d], ss = sinp[l * 32 + d];
                    v = v * cc + ((n & 1) ? other : -other) * ss;
                }
                if (ACT) v = 0.5f * v * (1.0f + erff(v * 0.70710678118654752f));
                if (OBF16) {
                    ((ushort_t*)Cp)[m * N + n] = f2bf(v);
                } else {
                    if (resid) v += resid[m * N + n];
                    ((float*)Cp)[m * N + n] = v;
                }
            }
        }
}

// ---- staging helpers for attention V ------------------------------------
__device__ __forceinline__ void load8(const float* p, ushort_t* o) {
    float4 a = *reinterpret_cast<const float4*>(p);
    float4 b = *reinterpret_cast<const float4*>(p + 4);
    o[0] = f2bf(a.x); o[1] = f2bf(a.y); o[2] = f2bf(a.z); o[3] = f2bf(a.w);
    o[4] = f2bf(b.x); o[5] = f2bf(b.y); o[6] = f2bf(b.z); o[7] = f2bf(b.w);
}
__device__ __forceinline__ void load8(const ushort_t* p, ushort_t* o) {
    uint4 u = *reinterpret_cast<const uint4*>(p);
    o[0] = u.x & 0xFFFF; o[1] = u.x >> 16; o[2] = u.y & 0xFFFF; o[3] = u.y >> 16;
    o[4] = u.z & 0xFFFF; o[5] = u.z >> 16; o[6] = u.w & 0xFFFF; o[7] = u.w >> 16;
}

// ---- MFMA flash attention ------------------------------------------------
// grid (qt, h, b); 4 waves x 16 queries; keys = 1024 in blocks of 128.
// Q,K bf16 [rows][256] slice at h*32; V (f32 or bf16); out bf16 (+lepe f32).
template<typename VT>
__global__ __launch_bounds__(256) void attn_mfma(
        const ushort_t* __restrict__ Q, const ushort_t* __restrict__ K,
        const VT* __restrict__ V, const float* __restrict__ mask,
        const float* __restrict__ lepe, ushort_t* __restrict__ out, int nq) {
    __shared__ __align__(16) ushort_t Vt[32 * 136];       // [d][key] keys 0..127
    __shared__ __align__(16) ushort_t Pl[4][16 * 136];    // per-wave [q][key]
    int tid = threadIdx.x;
    int wave = tid >> 6, lane = tid & 63;
    int quad = lane >> 4, l16 = lane & 15;
    int qt = blockIdx.x, h = blockIdx.y, b = blockIdx.z;
    int qbase = qt * 64 + wave * 16;

    // Q fragment: A[m=l16][k=quad*8+j]
    bf16x8 qfrag = *reinterpret_cast<const bf16x8*>(
        Q + ((long)b * nq + qbase + l16) * E_ + h * KD_ + quad * 8);

    f32x4 acc_o[2];
    acc_o[0] = (f32x4){0.f, 0.f, 0.f, 0.f};
    acc_o[1] = (f32x4){0.f, 0.f, 0.f, 0.f};
    float lsum[4] = {0.f, 0.f, 0.f, 0.f};

    int kp = tid & 63;   // key pair for V staging
    int dq = tid >> 6;   // d-octet

    for (int kb = 0; kb < L_; kb += 128) {
        __syncthreads();   // prior iter PV reads of Vt done
        {   // stage V transposed: Vt[d][key], packed 2 keys per u32 write
            long r0 = ((long)b * L_ + kb + 2 * kp) * E_ + h * KD_ + dq * 8;
            ushort_t va[8], vb[8];
            load8(V + r0, va);
            load8(V + r0 + E_, vb);
#pragma unroll
            for (int i = 0; i < 8; ++i) {
                int d = dq * 8 + i;
                *reinterpret_cast<unsigned int*>(&Vt[d * 136 + 2 * kp]) =
                    (unsigned int)va[i] | ((unsigned int)vb[i] << 16);
            }
        }
        __syncthreads();

        // S phase: 8 key-tiles of 16
        for (int kt = 0; kt < 8; ++kt) {
            bf16x8 kf = *reinterpret_cast<const bf16x8*>(
                K + ((long)b * L_ + kb + kt * 16 + l16) * E_ + h * KD_ + quad * 8);
            f32x4 sa;
            if (mask) {
#pragma unroll
                for (int r = 0; r < 4; ++r)
                    sa[r] = mask[((long)h * L_ + qbase + quad * 4 + r) * L_ + kb + kt * 16 + l16];
            } else {
                sa = (f32x4){0.f, 0.f, 0.f, 0.f};
            }
            sa = __builtin_amdgcn_mfma_f32_16x16x32_bf16(qfrag, kf, sa, 0, 0, 0);
#pragma unroll
            for (int r = 0; r < 4; ++r) {
                float p = __expf(sa[r]);
                lsum[r] += p;
                Pl[wave][(quad * 4 + r) * 136 + kt * 16 + l16] = f2bf(p);
            }
        }

        // PV phase: 4 chunks of 32 keys
#pragma unroll
        for (int c = 0; c < 4; ++c) {
            bf16x8 pa = *reinterpret_cast<const bf16x8*>(
                &Pl[wave][l16 * 136 + c * 32 + quad * 8]);
#pragma unroll
            for (int dt = 0; dt < 2; ++dt) {
                bf16x8 vf = *reinterpret_cast<const bf16x8*>(
                    &Vt[(dt * 16 + l16) * 136 + c * 32 + quad * 8]);
                acc_o[dt] = __builtin_amdgcn_mfma_f32_16x16x32_bf16(pa, vf, acc_o[dt], 0, 0, 0);
            }
        }
    }

    // reduce lsum across the 16 columns (lanes l16)
#pragma unroll
    for (int off = 1; off < 16; off <<= 1) {
#pragma unroll
        for (int r = 0; r < 4; ++r) lsum[r] += __shfl_xor(lsum[r], off);
    }

#pragma unroll
    for (int dt = 0; dt < 2; ++dt)
#pragma unroll
        for (int r = 0; r < 4; ++r) {
            float v = acc_o[dt][r] / lsum[r];
            long oi = ((long)b * nq + qbase + quad * 4 + r) * E_ + h * KD_ + dt * 16 + l16;
            if (lepe) v += lepe[oi];
            out[oi] = f2bf(v);
        }
}

extern "C" void kernel_launch(void* const* d_in, const int* in_sizes, int n_in,
                              void* d_out, int out_size, void* d_ws, size_t ws_size,
                              hipStream_t stream) {
    const float* x        = (const float*)d_in[0];
    const float* queries  = (const float*)d_in[1];
    const float* sinp     = (const float*)d_in[2];
    const float* cosp     = (const float*)d_in[3];
    const float* mask     = (const float*)d_in[4];
    const float* ln1_g    = (const float*)d_in[5];
    const float* ln1_b    = (const float*)d_in[6];
    const float* ln2_g    = (const float*)d_in[7];
    const float* ln2_b    = (const float*)d_in[8];
    const float* wq       = (const float*)d_in[9];
    const float* bq       = (const float*)d_in[10];
    const float* wk       = (const float*)d_in[11];
    const float* bk       = (const float*)d_in[12];
    const float* wv       = (const float*)d_in[13];
    const float* bv       = (const float*)d_in[14];
    const float* lepe_w   = (const float*)d_in[15];
    const float* lepe_b   = (const float*)d_in[16];
    const float* wo       = (const float*)d_in[17];
    const float* bo       = (const float*)d_in[18];
    const float* fc1_w    = (const float*)d_in[19];
    const float* fc1_b    = (const float*)d_in[20];
    const float* fc2_w    = (const float*)d_in[21];
    const float* fc2_b    = (const float*)d_in[22];
    const float* pos_w    = (const float*)d_in[23];
    const float* pos_b    = (const float*)d_in[24];
    const float* ca_in_w  = (const float*)d_in[25];
    const float* ca_in_b  = (const float*)d_in[26];
    const float* ca_out_w = (const float*)d_in[27];
    const float* ca_out_b = (const float*)d_in[28];

    float* ws = (float*)d_ws;
    const long SZ = (long)B_ * L_ * E_;       // 2,097,152
    float* X    = ws;                 // f32 tile
    float* Vb   = ws + SZ;            // f32 tile
    float* LEP  = ws + 2 * SZ;        // f32 tile
    float* Q2   = LEP;                // CA residual (LEP dead after attn)
    ushort_t* U = (ushort_t*)(ws + 3 * SZ);
    ushort_t* HN_u  = U;              // 2M ushorts
    ushort_t* Qb_u  = U + SZ;
    ushort_t* Kb_u  = U + 2 * SZ;
    ushort_t* ATT_u = U + 3 * SZ;
    // EXT tile U+4*SZ .. U+5*SZ
    ushort_t* HID_u = Qb_u;           // spans Qb,Kb,ATT,EXT = 8M ushorts
    // CA aliases:
    ushort_t* QLN_u  = HN_u;
    ushort_t* QP_u   = HN_u + 131072;
    ushort_t* CAO_u  = HN_u + 262144;
    ushort_t* KP_u   = Qb_u;
    ushort_t* VP_u   = Kb_u;
    ushort_t* QHID_u = ATT_u;         // 512*1024

    float* XOUT = (float*)d_out;
    float* QOUT = (float*)d_out + 2097152;

    dim3 blk(256);
    const int rows = B_ * L_;  // 8192

    // ---- main path ----
    posconv_ln_kernel<<<rows, blk, 0, stream>>>(x, pos_w, pos_b, ln1_g, ln1_b, X, HN_u);
    gemm_t<1,1,1,0><<<dim3(64, 4), blk, 0, stream>>>(HN_u, wq, bq, Qb_u, nullptr, rows, 256, 256, 1.0f, sinp, cosp);
    gemm_t<1,1,1,0><<<dim3(64, 4), blk, 0, stream>>>(HN_u, wk, bk, Kb_u, nullptr, rows, 256, 256, SCALING_, sinp, cosp);
    gemm_t<1,0,0,0><<<dim3(64, 4), blk, 0, stream>>>(HN_u, wv, bv, Vb, nullptr, rows, 256, 256, 1.0f, nullptr, nullptr);
    lepe_kernel<<<rows, blk, 0, stream>>>(Vb, lepe_w, lepe_b, LEP);
    attn_mfma<float><<<dim3(16, 8, 8), blk, 0, stream>>>(Qb_u, Kb_u, Vb, mask, LEP, ATT_u, L_);
    gemm_t<1,0,0,0><<<dim3(64, 4), blk, 0, stream>>>(ATT_u, wo, bo, X, X, rows, 256, 256, 1.0f, nullptr, nullptr);
    ln_kernel<<<rows, blk, 0, stream>>>(X, ln2_g, ln2_b, HN_u);
    gemm_t<1,1,0,1><<<dim3(64, 16), blk, 0, stream>>>(HN_u, fc1_w, fc1_b, HID_u, nullptr, rows, 1024, 256, 1.0f, nullptr, nullptr);
    gemm_t<1,0,0,0><<<dim3(64, 4), blk, 0, stream>>>(HID_u, fc2_w, fc2_b, XOUT, X, rows, 256, 1024, 1.0f, nullptr, nullptr);

    // ---- cross-attention path ----
    ln_kernel<<<B_ * NQ_, blk, 0, stream>>>(queries, ln1_g, ln1_b, QLN_u);
    gemm_t<1,1,0,0><<<dim3(4, 4), blk, 0, stream>>>(QLN_u, ca_in_w, ca_in_b, QP_u, nullptr, 512, 256, 256, 1.0f, nullptr, nullptr);
    gemm_t<0,1,0,0><<<dim3(64, 4), blk, 0, stream>>>(XOUT, ca_in_w + 65536, ca_in_b + 256, KP_u, nullptr, rows, 256, 256, SCALING_, nullptr, nullptr);
    gemm_t<0,1,0,0><<<dim3(64, 4), blk, 0, stream>>>(XOUT, ca_in_w + 131072, ca_in_b + 512, VP_u, nullptr, rows, 256, 256, 1.0f, nullptr, nullptr);
    attn_mfma<ushort_t><<<dim3(1, 8, 8), blk, 0, stream>>>(QP_u, KP_u, VP_u, nullptr, nullptr, CAO_u, NQ_);
    gemm_t<1,0,0,0><<<dim3(4, 4), blk, 0, stream>>>(CAO_u, ca_out_w, ca_out_b, Q2, queries, 512, 256, 256, 1.0f, nullptr, nullptr);
    ln_kernel<<<B_ * NQ_, blk, 0, stream>>>(Q2, ln2_g, ln2_b, QLN_u);
    gemm_t<1,1,0,1><<<dim3(4, 16), blk, 0, stream>>>(QLN_u, fc1_w, fc1_b, QHID_u, nullptr, 512, 1024, 256, 1.0f, nullptr, nullptr);
    gemm_t<1,0,0,0><<<dim3(4, 4), blk, 0, stream>>>(QHID_u, fc2_w, fc2_b, QOUT, Q2, 512, 256, 1024, 1.0f, nullptr, nullptr);
}